// Round 6
// baseline (102.629 us; speedup 1.0000x reference)
//
#include <hip/hip_runtime.h>
#include <math.h>

// Chamfer distance via MFMA, fp16 quantized / fp32 accumulate.
// K-packing: A_row = (-2ax,-2ay,-2az, 1, sqa, 0,0,0), B_col = (bx,by,bz, sqb, 1, 0,0,0)
// => MFMA dot = sqa + sqb - 2 a.b = full squared distance (from quantized coords).
//
// R15 vs R14: R14's occupancy null (8 waves/SIMD = no change) proves the
// sweep is ISSUE-bound, not stall-bound. R11 calibration: ~1125 cyc/iter vs
// ~160 cyc source-visible issue -> ~100+ hidden VALU instrs/iter. R13's
// width-halving couldn't touch them (per-MFMA splice totals unchanged).
// Prime suspect: B-operand assembly (union splice of ds_read_b64 + constant
// upper halves) per MFMA. Fix: LDS holds PRE-BUILT 16-byte MFMA fragments
// (x,y,z,|b|^2,1,0,0,0 as 8 halves); inner loop is ONE ds_read_b128 with
// immediate offset straight into the MFMA operand -- zero assembly VALU,
// zero per-step address math (unroll 8 -> imm offsets off one base reg).
// Each B read feeds 2 MFMAs (wave owns 2 row-groups = 64 rows) halving
// ds_read/MFMA; min3 folds via dA/dB pairing. 4 waves/SIMD (proven regime),
// 1 block/CU (128KB LDS), 3 dispatches, no grid.sync.

typedef _Float16 half8    __attribute__((ext_vector_type(8)));
typedef float    floatx16 __attribute__((ext_vector_type(16)));

constexpr int NPTS = 16384;    // fixed problem size
constexpr int HALF = 8192;     // B points per block (8192 * 16B = 128 KB LDS)
constexpr int ROWS = 256;      // A-rows per block (4 rgp * 64)
constexpr int BLK  = 1024;     // 16 waves = 4/SIMD at 1 block/CU

// ---- pack one point into a 4-half fragment (x,y,z,|p|^2) ----
__device__ __forceinline__ uint2 pack_point(const float* __restrict__ P, int j)
{
    float x = P[3*j], y = P[3*j+1], z = P[3*j+2];
    _Float16 hx = (_Float16)x, hy = (_Float16)y, hz = (_Float16)z;
    float qx = (float)hx, qy = (float)hy, qz = (float)hz;
    _Float16 hw = (_Float16)(qx*qx + qy*qy + qz*qz);
    union { _Float16 h[4]; uint2 u; } p;
    p.h[0] = hx; p.h[1] = hy; p.h[2] = hz; p.h[3] = hw;
    return p.u;
}

// ---- pack one point into a FULL 16-byte MFMA B-fragment ----
__device__ __forceinline__ uint4 pack_frag16(const float* __restrict__ P, int j)
{
    float x = P[3*j], y = P[3*j+1], z = P[3*j+2];
    _Float16 hx = (_Float16)x, hy = (_Float16)y, hz = (_Float16)z;
    float qx = (float)hx, qy = (float)hy, qz = (float)hz;
    _Float16 hw = (_Float16)(qx*qx + qy*qy + qz*qz);
    union { _Float16 h[8]; uint4 u; } f;
    f.h[0] = hx; f.h[1] = hy; f.h[2] = hz; f.h[3] = hw;
    f.h[4] = (_Float16)1.0f;
    f.h[5] = (_Float16)0.0f; f.h[6] = (_Float16)0.0f; f.h[7] = (_Float16)0.0f;
    return f.u;
}

// Sweep: block = (256 A-rows) x (one B half); writes per-(dir,row,half) partial min^2.
__global__ __launch_bounds__(BLK, 4) void chamfer_sweep_kernel(
    const float* __restrict__ P1, const float* __restrict__ P2,
    float* __restrict__ part, int n1, int n2)
{
    __shared__ uint4 sB[HALF];            // pre-built 16B B fragments (128 KB)
    __shared__ float sRowMin[4][ROWS];    // per-B-quarter row mins (4 KB)

    const int dir   = blockIdx.z;
    const int half  = blockIdx.y;
    const float* PA = dir == 0 ? P1 : P2;
    const float* PB = dir == 0 ? P2 : P1;
    const int nA    = dir == 0 ? n1 : n2;
    const int nB    = dir == 0 ? n2 : n1;

    const int tid  = threadIdx.x;
    const int wave = tid >> 6;
    const int lane = tid & 63;
    const int n    = lane & 31;
    const int g    = lane >> 5;
    const bool g0  = (g == 0);
    const int rgp  = wave & 3;        // row-group-pair: rows rgp*64 .. rgp*64+63
    const int bq   = wave >> 2;       // B-quarter of the half (2048 pts)

    // ---- pack this B half into LDS as ready MFMA fragments ----
    for (int j = tid; j < HALF; j += BLK) {
        int jg = half * HALF + j;
        int jj = jg < nB ? jg : nB - 1;      // pad with dup of last point
        sB[j] = pack_frag16(PB, jj);
    }

    // ---- two A fragments (rows rgp*64+n and rgp*64+32+n) ----
    const _Float16 h0 = (_Float16)0.0f;
    const _Float16 m2 = (_Float16)(-2.0f);
    half8 af0, af1;
    {
        int abase = blockIdx.x * ROWS + rgp * 64 + n;
        int j0 = abase      < nA ? abase      : nA - 1;
        int j1 = abase + 32 < nA ? abase + 32 : nA - 1;
        union { uint2 u; _Float16 h[4]; } a0, a1;
        a0.u = pack_point(PA, j0);
        a1.u = pack_point(PA, j1);
        af0[0] = g0 ? (_Float16)(a0.h[0] * m2) : h0;
        af0[1] = g0 ? (_Float16)(a0.h[1] * m2) : h0;
        af0[2] = g0 ? (_Float16)(a0.h[2] * m2) : h0;
        af0[3] = g0 ? (_Float16)1.0f : h0;
        af0[4] = g0 ? a0.h[3] : h0;
        af0[5] = h0; af0[6] = h0; af0[7] = h0;
        af1[0] = g0 ? (_Float16)(a1.h[0] * m2) : h0;
        af1[1] = g0 ? (_Float16)(a1.h[1] * m2) : h0;
        af1[2] = g0 ? (_Float16)(a1.h[2] * m2) : h0;
        af1[3] = g0 ? (_Float16)1.0f : h0;
        af1[4] = g0 ? a1.h[3] : h0;
        af1[5] = h0; af1[6] = h0; af1[7] = h0;
    }

    __syncthreads();

    floatx16 rowmin0, rowmin1;
#pragma unroll
    for (int r = 0; r < 16; ++r) { rowmin0[r] = 1e30f; rowmin1[r] = 1e30f; }
    const floatx16 zacc = {};

    // ---- sweep own quarter: 32 iters x (2 ds_read_b128 + 4 MFMA + 32 min3).
    //      B fragments load DIRECTLY into the MFMA operand (no splice VALU);
    //      unroll 8 -> all LDS addresses are imm offsets off one base. ----
    const half8* qb = (const half8*)sB + bq * 2048 + n;   // g0/g1 broadcast
#pragma unroll 8
    for (int it = 0; it < 32; ++it) {
        half8 B0 = qb[it * 64];
        half8 B1 = qb[it * 64 + 32];

        floatx16 dA = __builtin_amdgcn_mfma_f32_32x32x16_f16(af0, B0, zacc, 0, 0, 0);
        floatx16 dB = __builtin_amdgcn_mfma_f32_32x32x16_f16(af0, B1, zacc, 0, 0, 0);
#pragma unroll
        for (int r = 0; r < 16; ++r)
            rowmin0[r] = fminf(fminf(rowmin0[r], dA[r]), dB[r]);   // v_min3

        dA = __builtin_amdgcn_mfma_f32_32x32x16_f16(af1, B0, zacc, 0, 0, 0);
        dB = __builtin_amdgcn_mfma_f32_32x32x16_f16(af1, B1, zacc, 0, 0, 0);
#pragma unroll
        for (int r = 0; r < 16; ++r)
            rowmin1[r] = fminf(fminf(rowmin1[r], dA[r]), dB[r]);   // v_min3
    }

    // ---- reduce across the 32 cols (xor-shuffle; masks stay within g-half) ----
#pragma unroll
    for (int mask = 1; mask <= 16; mask <<= 1)
#pragma unroll
        for (int r = 0; r < 16; ++r) {
            rowmin0[r] = fminf(rowmin0[r], __shfl_xor(rowmin0[r], mask));
            rowmin1[r] = fminf(rowmin1[r], __shfl_xor(rowmin1[r], mask));
        }

    if (n == 0) {
#pragma unroll
        for (int r = 0; r < 16; ++r) {
            int rr = rgp * 64 + g * 4 + ((r & 3) + 8 * (r >> 2));   // C/D row map
            sRowMin[bq][rr]      = rowmin0[r];
            sRowMin[bq][rr + 32] = rowmin1[r];
        }
    }
    __syncthreads();

    // ---- combine quarters -> one partial per (dir,row,half) ----
    if (tid < ROWS) {
        float m = fminf(fminf(sRowMin[0][tid], sRowMin[1][tid]),
                        fminf(sRowMin[2][tid], sRowMin[3][tid]));
        int grow = blockIdx.x * ROWS + tid;
        if (grow < nA)
            part[(size_t)(((dir << 14) + grow) << 1) + half] = m;
    }
}

// Per-row min over 2 half-partials -> sqrt -> block sum -> atomicAdd(out)
__global__ __launch_bounds__(256) void reduce_kernel(
    const float* __restrict__ part, float* __restrict__ out,
    int n1, int n2)
{
    __shared__ float s[256];
    int rr = blockIdx.x * 256 + threadIdx.x;    // [0, 2*16384)
    int dir = rr >> 14, row = rr & 16383;
    float acc = 0.0f;
    if (row < (dir == 0 ? n1 : n2)) {
        const float2 v = ((const float2*)part)[rr];
        acc = sqrtf(fmaxf(fminf(v.x, v.y), 0.0f));
    }
    s[threadIdx.x] = acc;
    __syncthreads();
    for (int w = 128; w > 0; w >>= 1) {
        if (threadIdx.x < w) s[threadIdx.x] += s[threadIdx.x + w];
        __syncthreads();
    }
    if (threadIdx.x == 0) atomicAdd(out, s[0]);
}

extern "C" void kernel_launch(void* const* d_in, const int* in_sizes, int n_in,
                              void* d_out, int out_size, void* d_ws, size_t ws_size,
                              hipStream_t stream) {
    const float* P1 = (const float*)d_in[0];
    const float* P2 = (const float*)d_in[1];
    const int n1 = in_sizes[0] / 3;   // 16384
    const int n2 = in_sizes[1] / 3;   // 16384
    float* part = (float*)d_ws;       // [2 dirs][16384 rows][2 halves] = 256 KB
    float* out  = (float*)d_out;

    hipMemsetAsync(out, 0, sizeof(float), stream);   // capture-safe

    {   // 64 row-blocks x 2 halves x 2 dirs = 256 blocks = exactly 1/CU
        dim3 grid(NPTS / ROWS, 2, 2);
        chamfer_sweep_kernel<<<grid, BLK, 0, stream>>>(P1, P2, part, n1, n2);
    }
    reduce_kernel<<<(2 * NPTS) / 256, 256, 0, stream>>>(part, out, n1, n2);
}

// Round 7
// 90.460 us; speedup vs baseline: 1.1345x; 1.1345x over previous
//
#include <hip/hip_runtime.h>
#include <math.h>

// Chamfer distance via MFMA, fp16 quantized / fp32 accumulate.
// K-packing: A_row = (-2ax,-2ay,-2az, 1, sqa, 0,0,0), B_col = (bx,by,bz, sqb, 1, 0,0,0)
// => MFMA dot = sqa + sqb - 2 a.b = full squared distance (from quantized coords).
//
// R16 vs R15: R15's counters showed VGPR_Count=64 + ~100MB/dispatch scratch
// traffic -> unroll-8 spill disaster; operand theory untested. Bigger lever,
// previously unused: both directions sweep the SAME distance matrix. This
// round computes the matrix ONCE and folds row-mins AND col-mins:
// MFMAs/LDS-reads/iterations HALVE (524K -> 262K MFMA; MFMA floor 6.9 -> 3.5us),
// VALU folds ~constant. Block = 512 A-rows (16 waves x 32) x 2048 B-cols
// (32KB LDS, pre-built 16B fragments, ds_read_b128 straight into the MFMA
// operand). Grid 32x8 = 256 = 1/CU, 4 waves/SIMD (proven best regime),
// unroll 2 ONLY (R15 lesson). Col-min: per-MFMA register tree + shfl_xor(32)
// + LDS atomicMin(int); block results -> global int atomicMin min-buffers
// (float-bits int-compare is exact for >=0; wrong-negative picks clamp to 0
// identically to reference's max(min,0)). Contention tiny: 8 blocks/row,
// 32 blocks/col. Init one hipMemsetAsync(0x7F, 128KB); single-block reduce
// writes out[0] directly (no atomic, no zero-init). 3 dispatches, no grid.sync.

typedef _Float16 half8    __attribute__((ext_vector_type(8)));
typedef float    floatx16 __attribute__((ext_vector_type(16)));

constexpr int NPTS  = 16384;   // fixed problem size
constexpr int SEG   = 2048;    // B cols per block (2048 * 16B = 32 KB LDS)
constexpr int AROWS = 512;     // A rows per block (16 waves * 32)
constexpr int BLK   = 1024;    // 16 waves = 4/SIMD at 1 block/CU

// ---- pack one point into a 4-half fragment (x,y,z,|p|^2) ----
__device__ __forceinline__ uint2 pack_point(const float* __restrict__ P, int j)
{
    float x = P[3*j], y = P[3*j+1], z = P[3*j+2];
    _Float16 hx = (_Float16)x, hy = (_Float16)y, hz = (_Float16)z;
    float qx = (float)hx, qy = (float)hy, qz = (float)hz;
    _Float16 hw = (_Float16)(qx*qx + qy*qy + qz*qz);
    union { _Float16 h[4]; uint2 u; } p;
    p.h[0] = hx; p.h[1] = hy; p.h[2] = hz; p.h[3] = hw;
    return p.u;
}

// ---- pack one point into a FULL 16-byte MFMA B-fragment ----
__device__ __forceinline__ uint4 pack_frag16(const float* __restrict__ P, int j)
{
    float x = P[3*j], y = P[3*j+1], z = P[3*j+2];
    _Float16 hx = (_Float16)x, hy = (_Float16)y, hz = (_Float16)z;
    float qx = (float)hx, qy = (float)hy, qz = (float)hz;
    _Float16 hw = (_Float16)(qx*qx + qy*qy + qz*qz);
    union { _Float16 h[8]; uint4 u; } f;
    f.h[0] = hx; f.h[1] = hy; f.h[2] = hz; f.h[3] = hw;
    f.h[4] = (_Float16)1.0f;
    f.h[5] = (_Float16)0.0f; f.h[6] = (_Float16)0.0f; f.h[7] = (_Float16)0.0f;
    return f.u;
}

// Symmetric sweep: block = (512 A-rows) x (2048 B-cols); folds rowmin AND colmin.
__global__ __launch_bounds__(BLK, 4) void chamfer_sym_kernel(
    const float* __restrict__ P1, const float* __restrict__ P2,
    int* __restrict__ rowmin, int* __restrict__ colmin, int n1, int n2)
{
    __shared__ uint4 sB[SEG];        // pre-built 16B B fragments (32 KB)
    __shared__ int   sColMin[SEG];   // block-level col mins, float bits (8 KB)

    const int tid  = threadIdx.x;
    const int wave = tid >> 6;
    const int lane = tid & 63;
    const int n    = lane & 31;
    const int g    = lane >> 5;
    const bool g0  = (g == 0);

    // ---- init LDS colmin + pack this B segment as ready MFMA fragments ----
    const int cbase = blockIdx.y * SEG;
    for (int j = tid; j < SEG; j += BLK) {
        sColMin[j] = 0x7F7F7F7F;
        int jj = cbase + j;
        if (jj >= n2) jj = n2 - 1;           // pad = dup of last point (min-safe)
        sB[j] = pack_frag16(P2, jj);
    }

    // ---- A fragment for this wave's 32 rows ----
    const _Float16 h0 = (_Float16)0.0f;
    half8 af;
    {
        int arow = blockIdx.x * AROWS + wave * 32 + n;
        int j = arow < n1 ? arow : n1 - 1;   // pad = dup (row discarded later)
        union { uint2 u; _Float16 h[4]; } au; au.u = pack_point(P1, j);
        const _Float16 m2 = (_Float16)(-2.0f);
        af[0] = g0 ? (_Float16)(au.h[0] * m2) : h0;
        af[1] = g0 ? (_Float16)(au.h[1] * m2) : h0;
        af[2] = g0 ? (_Float16)(au.h[2] * m2) : h0;
        af[3] = g0 ? (_Float16)1.0f : h0;
        af[4] = g0 ? au.h[3] : h0;
        af[5] = h0; af[6] = h0; af[7] = h0;
    }

    __syncthreads();

    floatx16 rmin;
#pragma unroll
    for (int r = 0; r < 16; ++r) rmin[r] = 1e30f;
    const floatx16 zacc = {};

    // ---- sweep: 32 steps x (2 ds_read_b128 -> 2 MFMA -> row folds + col trees) ----
    const half8* qb = (const half8*)sB + n;      // g0/g1 broadcast same addr
#pragma unroll 2
    for (int t = 0; t < SEG / 64; ++t) {
        half8 B0 = qb[t * 64];
        half8 B1 = qb[t * 64 + 32];

        floatx16 dA = __builtin_amdgcn_mfma_f32_32x32x16_f16(af, B0, zacc, 0, 0, 0);
        floatx16 dB = __builtin_amdgcn_mfma_f32_32x32x16_f16(af, B1, zacc, 0, 0, 0);

        // row mins: 16 x v_min3
#pragma unroll
        for (int r = 0; r < 16; ++r)
            rmin[r] = fminf(fminf(rmin[r], dA[r]), dB[r]);

        // col mins: each lane's 16 regs are ONE column (col = lane&31) over 16 rows
        float cA = dA[0], cB = dB[0];
#pragma unroll
        for (int r = 1; r + 1 < 16; r += 2) {
            cA = fminf(fminf(cA, dA[r]), dA[r + 1]);     // v_min3 chain
            cB = fminf(fminf(cB, dB[r]), dB[r + 1]);
        }
        cA = fminf(cA, dA[15]);
        cB = fminf(cB, dB[15]);
        // merge the two 16-row halves (g0 rows vs g1 rows)
        cA = fminf(cA, __shfl_xor(cA, 32));
        cB = fminf(cB, __shfl_xor(cB, 32));
        if (g0) {   // halves now identical; one LDS atomic per col
            atomicMin(&sColMin[t * 64 + n],      __float_as_int(cA));
            atomicMin(&sColMin[t * 64 + 32 + n], __float_as_int(cB));
        }
    }

    // ---- rowmin: reduce across the 32 cols (xor-shuffle within n-group) ----
#pragma unroll
    for (int mask = 1; mask <= 16; mask <<= 1)
#pragma unroll
        for (int r = 0; r < 16; ++r)
            rmin[r] = fminf(rmin[r], __shfl_xor(rmin[r], mask));

    if (n == 0) {
        int rbase = blockIdx.x * AROWS + wave * 32 + g * 4;
#pragma unroll
        for (int r = 0; r < 16; ++r) {
            int row = rbase + (r & 3) + 8 * (r >> 2);    // C/D row map
            if (row < n1)
                atomicMin(&rowmin[row], __float_as_int(rmin[r]));
        }
    }

    // ---- colmin: LDS -> global (contention: 32 blocks per col) ----
    __syncthreads();
    for (int j = tid; j < SEG; j += BLK) {
        int c = cbase + j;
        if (c < n2) atomicMin(&colmin[c], sColMin[j]);
    }
}

// Single block: sum sqrt(max(min^2,0)) over rows + cols, write out[0] directly.
__global__ __launch_bounds__(1024) void reduce_kernel(
    const int* __restrict__ mins, float* __restrict__ out, int n1, int n2)
{
    __shared__ float s[1024];
    float acc = 0.0f;
    for (int j = threadIdx.x; j < 2 * NPTS; j += 1024) {
        bool isrow = j < NPTS;
        int idx = isrow ? j : j - NPTS;
        if (idx < (isrow ? n1 : n2))
            acc += sqrtf(fmaxf(__int_as_float(mins[j]), 0.0f));
    }
    s[threadIdx.x] = acc;
    __syncthreads();
    for (int w = 512; w > 0; w >>= 1) {
        if (threadIdx.x < w) s[threadIdx.x] += s[threadIdx.x + w];
        __syncthreads();
    }
    if (threadIdx.x == 0) out[0] = s[0];
}

extern "C" void kernel_launch(void* const* d_in, const int* in_sizes, int n_in,
                              void* d_out, int out_size, void* d_ws, size_t ws_size,
                              hipStream_t stream) {
    const float* P1 = (const float*)d_in[0];
    const float* P2 = (const float*)d_in[1];
    const int n1 = in_sizes[0] / 3;   // 16384
    const int n2 = in_sizes[1] / 3;   // 16384

    int* rowmin = (int*)d_ws;                 // [NPTS] float-bits min^2 per A-row
    int* colmin = rowmin + NPTS;              // [NPTS] float-bits min^2 per B-col
    float* out  = (float*)d_out;

    // 0x7F7F7F7F as float = 3.4e38: any real min^2 replaces it.
    hipMemsetAsync(d_ws, 0x7F, 2 * NPTS * sizeof(int), stream);

    {   // 32 row-blocks x 8 col-segments = 256 blocks = exactly 1/CU
        dim3 grid(NPTS / AROWS, NPTS / SEG);
        chamfer_sym_kernel<<<grid, BLK, 0, stream>>>(P1, P2, rowmin, colmin, n1, n2);
    }
    reduce_kernel<<<1, 1024, 0, stream>>>(rowmin, out, n1, n2);
}

// Round 8
// 77.057 us; speedup vs baseline: 1.3319x; 1.1739x over previous
//
#include <hip/hip_runtime.h>
#include <math.h>

// Chamfer distance via MFMA, fp16 quantized / fp32 accumulate.
// K-packing: A_row = (-2ax,-2ay,-2az, 1, sqa, 0,0,0), B_col = (bx,by,bz, sqb, 1, 0,0,0)
// => MFMA dot = sqa + sqb - 2 a.b = full squared distance (from quantized coords).
//
// R17 vs R16: R16 (symmetric fold) regressed as the fold VALU is the binding
// pipe and is proportional to DISTANCES, not MFMAs -- reverted to R13's
// structure wholesale. R17 tests the one theory fitting all 8 rounds of data
// (incl. R15's VGPR_Count=64 + spill = 64/64 arch/acc split): builtin MFMA
// results land in AGPRs, so every d[r] fold pays v_accvgpr_read and every
// MFMA re-zeros its C tuple -> the stable ~4x VALU inflation. Fix: inline-asm
// v_mfma with "=&v"/"v" constraints (AGPR impossible; one shared zero-C
// tuple input, never rewritten). Raw asm loses compiler hazard handling, so
// the loop is software-pipelined 1 step deep: fold step t's D-tuples while
// step t+1's MFMAs are in flight; sched_barrier(0) pins the fold after the
// MFMA issue (>=20-50 independent cycles between D write and VALU read,
// above worst-case MFMA wait-state requirements, no s_nop waste).
// Macro-structure = R13: 2 dispatches (memset4B + fused kernel), full B
// cloud packed in-kernel to 128KB LDS, BLK=1024 = 16 waves = 4/SIMD,
// waves = 4 row-groups x 4 B-quarters, no grid.sync.

typedef _Float16 half8    __attribute__((ext_vector_type(8)));
typedef float    floatx16 __attribute__((ext_vector_type(16)));

constexpr int NPTS = 16384;    // padded cloud size (128 KB LDS), fixed problem
constexpr int ROWS = 128;      // A-rows per block (4 row-groups * 32)
constexpr int BLK  = 1024;     // 16 waves = 4/SIMD at 1 block/CU

// ---- pack one point into an f16 fragment (x,y,z,|p|^2) ----
__device__ __forceinline__ uint2 pack_point(const float* __restrict__ P, int j)
{
    float x = P[3*j], y = P[3*j+1], z = P[3*j+2];
    _Float16 hx = (_Float16)x, hy = (_Float16)y, hz = (_Float16)z;
    float qx = (float)hx, qy = (float)hy, qz = (float)hz;
    _Float16 hw = (_Float16)(qx*qx + qy*qy + qz*qz);
    union { _Float16 h[4]; uint2 u; } p;
    p.h[0] = hx; p.h[1] = hy; p.h[2] = hz; p.h[3] = hw;
    return p.u;
}

// One fused kernel: pack B->LDS, pack own A-rows->regs, sweep, reduce, atomicAdd.
__global__ __launch_bounds__(BLK, 4) void chamfer_all_kernel(
    const float* __restrict__ P1, const float* __restrict__ P2,
    float* __restrict__ out, int n1, int n2)
{
    __shared__ uint2 sB[NPTS];            // packed B cloud
    __shared__ float sRowMin[4][ROWS];    // per-B-quarter row mins
    __shared__ float sRed[ROWS];          // final per-row sqrt'd values

    const int dir   = blockIdx.z;
    const float* PA = dir == 0 ? P1 : P2;
    const float* PB = dir == 0 ? P2 : P1;
    const int nA    = dir == 0 ? n1 : n2;
    const int nB    = dir == 0 ? n2 : n1;

    const int tid  = threadIdx.x;
    const int wave = tid >> 6;
    const int lane = tid & 63;
    const int n    = lane & 31;
    const int g    = lane >> 5;
    const bool g0  = (g == 0);
    const int wr   = wave & 3;        // row-group: rows wr*32 .. wr*32+31
    const int wq   = wave >> 2;       // B-quarter index

    // ---- pack the FULL B cloud into LDS (reads are L2-resident, 192 KB) ----
    for (int j = tid; j < NPTS; j += BLK) {
        int jj = j < nB ? j : nB - 1;        // pad with dup of last point
        sB[j] = pack_point(PB, jj);
    }

    // ---- A fragment: pack own row directly from fp32 points ----
    const _Float16 h0 = (_Float16)0.0f;
    half8 af;
    {
        int arow = blockIdx.x * ROWS + wr * 32 + n;
        int j = arow < nA ? arow : nA - 1;
        union { uint2 u; _Float16 h[4]; } au; au.u = pack_point(PA, j);
        const _Float16 m2 = (_Float16)(-2.0f);
        af[0] = g0 ? (_Float16)(au.h[0] * m2) : h0;
        af[1] = g0 ? (_Float16)(au.h[1] * m2) : h0;
        af[2] = g0 ? (_Float16)(au.h[2] * m2) : h0;
        af[3] = g0 ? (_Float16)1.0f : h0;
        af[4] = g0 ? au.h[3] : h0;
        af[5] = h0; af[6] = h0; af[7] = h0;
    }

    __syncthreads();

    floatx16 rowmin;
#pragma unroll
    for (int r = 0; r < 16; ++r) rowmin[r] = 1e30f;
    floatx16 zacc;                        // shared zero-C tuple (VGPRs, set once)
#pragma unroll
    for (int r = 0; r < 16; ++r) zacc[r] = 0.0f;

    // Persistent B-operand quads: upper pair (1.0h,0 | 0,0) written ONCE;
    // per-step ds_read_b64 lands directly in the lower pair.
    union BF { half8 v; unsigned u[4]; uint2 lo; };
    BF bu0, bu1;
    { union { _Float16 h[2]; unsigned u; } q;
      q.h[0] = (_Float16)1.0f; q.h[1] = h0;
      bu0.u[2] = q.u; bu0.u[3] = 0u;
      bu1.u[2] = q.u; bu1.u[3] = 0u; }

    // ---- sweep own B-quarter: 64 steps x (2 ds_read_b64 + 2 asm MFMA + 16 min3),
    //      software-pipelined 1 deep: fold step t while step t+1 MFMAs fly ----
    constexpr int QLEN = NPTS >> 2;            // 4096
    constexpr int NT   = QLEN / 64;            // 64 steps
    const uint2* qb = sB + wq * QLEN + n;      // g0/g1 broadcast same addr

#define LOADB(t)  do { bu0.lo = qb[(t) * 64]; bu1.lo = qb[(t) * 64 + 32]; } while (0)
    // v_mfma D,A,B,C with all-VGPR constraints: AGPR allocation impossible;
    // early-clobber keeps D disjoint from af/bu/zacc.
#define MFMA_PAIR(D0, D1) do { \
    asm("v_mfma_f32_32x32x16_f16 %0, %1, %2, %3" \
        : "=&v"(D0) : "v"(af), "v"(bu0.v), "v"(zacc)); \
    asm("v_mfma_f32_32x32x16_f16 %0, %1, %2, %3" \
        : "=&v"(D1) : "v"(af), "v"(bu1.v), "v"(zacc)); } while (0)
#define FOLD(P0, P1) do { \
    _Pragma("unroll") \
    for (int r = 0; r < 16; ++r) \
        rowmin[r] = fminf(fminf(rowmin[r], (P0)[r]), (P1)[r]); } while (0)

    floatx16 pA0, pA1, pB0, pB1;
    LOADB(0);
    MFMA_PAIR(pA0, pA1);
    for (int t = 1; t < NT - 1; t += 2) {
        LOADB(t);
        MFMA_PAIR(pB0, pB1);
        __builtin_amdgcn_sched_barrier(0);   // fold stays after the MFMA issue
        FOLD(pA0, pA1);
        LOADB(t + 1);
        MFMA_PAIR(pA0, pA1);
        __builtin_amdgcn_sched_barrier(0);
        FOLD(pB0, pB1);
    }
    LOADB(NT - 1);
    MFMA_PAIR(pB0, pB1);
    __builtin_amdgcn_sched_barrier(0);
    FOLD(pA0, pA1);                          // 16 min3 = 32+ cyc gap before pB read
    FOLD(pB0, pB1);
#undef LOADB
#undef MFMA_PAIR
#undef FOLD

    // ---- reduce across the 32 cols (xor-shuffle within n-group) ----
#pragma unroll
    for (int mask = 1; mask <= 16; mask <<= 1)
#pragma unroll
        for (int r = 0; r < 16; ++r)
            rowmin[r] = fminf(rowmin[r], __shfl_xor(rowmin[r], mask));

    if (n == 0) {
#pragma unroll
        for (int r = 0; r < 16; ++r) {
            int rr = wr * 32 + g * 4 + ((r & 3) + 8 * (r >> 2));   // C/D row map
            sRowMin[wq][rr] = rowmin[r];
        }
    }
    __syncthreads();

    // ---- combine quarters, sqrt, block-sum, one atomicAdd ----
    if (tid < ROWS) {
        float m = fminf(fminf(sRowMin[0][tid], sRowMin[1][tid]),
                        fminf(sRowMin[2][tid], sRowMin[3][tid]));
        int grow = blockIdx.x * ROWS + tid;
        sRed[tid] = (grow < nA) ? sqrtf(fmaxf(m, 0.0f)) : 0.0f;
    }
    __syncthreads();

    if (tid < 64) {
        float v = sRed[tid] + sRed[tid + 64];
#pragma unroll
        for (int mask = 1; mask <= 32; mask <<= 1)
            v += __shfl_xor(v, mask);
        if (tid == 0) atomicAdd(out, v);
    }
}

extern "C" void kernel_launch(void* const* d_in, const int* in_sizes, int n_in,
                              void* d_out, int out_size, void* d_ws, size_t ws_size,
                              hipStream_t stream) {
    const float* P1 = (const float*)d_in[0];
    const float* P2 = (const float*)d_in[1];
    const int n1 = in_sizes[0] / 3;   // 16384
    const int n2 = in_sizes[1] / 3;   // 16384
    float* out = (float*)d_out;

    hipMemsetAsync(out, 0, sizeof(float), stream);   // capture-safe

    dim3 grid(NPTS / ROWS, 1, 2);                    // 256 blocks = exactly 1/CU
    chamfer_all_kernel<<<grid, BLK, 0, stream>>>(P1, P2, out, n1, n2);
}